// Round 1
// baseline (227.566 us; speedup 1.0000x reference)
//
#include <hip/hip_runtime.h>
#include <math.h>

#define BB 32
#define LL 512
#define HH 768
#define PP 5
#define KK 5
#define CC 4
#define NN (BB*PP)   // 160

__device__ __forceinline__ float wredf(float v) {
  #pragma unroll
  for (int off = 32; off; off >>= 1) v += __shfl_xor(v, off, 64);
  return v;
}

// ---------------- kernel 0: proto norms, p_n, diversity loss, zero loss accum ----
__global__ __launch_bounds__(256) void k0_init(const float* __restrict__ proto,
    float* __restrict__ p_n, float* __restrict__ pnorm,
    double* __restrict__ loss_sum, float* __restrict__ out)
{
  __shared__ float s_red[4];
  __shared__ float s_bc;
  int tid = threadIdx.x, lane = tid & 63, wid = tid >> 6;
  if (tid == 0) loss_sum[0] = 0.0;
  for (int p = 0; p < PP; p++) {
    float ss = 0;
    for (int i = tid; i < HH; i += 256) { float v = proto[p*HH + i]; ss = fmaf(v, v, ss); }
    ss = wredf(ss);
    if (lane == 0) s_red[wid] = ss;
    __syncthreads();
    if (tid == 0) s_bc = sqrtf(s_red[0] + s_red[1] + s_red[2] + s_red[3]);
    __syncthreads();
    float nrm = s_bc;
    if (tid == 0) pnorm[p] = nrm;
    float inv = 1.0f / fmaxf(nrm, 1e-12f);
    for (int i = tid; i < HH; i += 256) p_n[p*HH + i] = proto[p*HH + i] * inv;
    __syncthreads();
  }
  // diversity: sum over i<j of relu(0.5 - D_ij)
  for (int i = 0; i < PP; i++) for (int j = i + 1; j < PP; j++) {
    float ss = 0;
    for (int t = tid; t < HH; t += 256) {
      float d = proto[i*HH + t] - proto[j*HH + t];
      ss = fmaf(d, d, ss);
    }
    ss = wredf(ss);
    if (lane == 0) s_red[wid] = ss;
    __syncthreads();
    if (tid == 0) {
      float d2 = s_red[0] + s_red[1] + s_red[2] + s_red[3];
      float D = sqrtf(fmaxf(d2, 1e-12f));
      s_bc = (i == 0 && j == 1 ? 0.0f : s_bc) + fmaxf(0.5f - D, 0.0f);
    }
    __syncthreads();
  }
  if (tid == 0) out[129] = s_bc;
}

// ---------------- kernel 1: cs[b*P+p][l] = cos(emb[b,l], proto[p]) ----------------
__global__ __launch_bounds__(256) void k1_cs(const float* __restrict__ emb,
    const float* __restrict__ p_n, float* __restrict__ cs)
{
  __shared__ float4 s_pn[PP][HH/4];   // 15 KB
  int tid = threadIdx.x, lane = tid & 63, wid = tid >> 6;
  for (int i = tid; i < PP*HH/4; i += 256) ((float4*)s_pn)[i] = ((const float4*)p_n)[i];
  __syncthreads();
  int gw = blockIdx.x * 4 + wid;        // 0..16383: one wave per (b,l)
  int b = gw >> 9, l = gw & 511;
  const float4* e4 = (const float4*)(emb + ((size_t)b * LL + l) * HH);
  float ss = 0, acc[PP] = {0, 0, 0, 0, 0};
  #pragma unroll
  for (int i = 0; i < 3; i++) {
    int idx = lane + i * 64;
    float4 x = e4[idx];
    ss = fmaf(x.x, x.x, fmaf(x.y, x.y, fmaf(x.z, x.z, fmaf(x.w, x.w, ss))));
    #pragma unroll
    for (int p = 0; p < PP; p++) {
      float4 w = s_pn[p][idx];
      acc[p] = fmaf(x.x, w.x, fmaf(x.y, w.y, fmaf(x.z, w.z, fmaf(x.w, w.w, acc[p]))));
    }
  }
  #pragma unroll
  for (int off = 32; off; off >>= 1) {
    ss += __shfl_xor(ss, off, 64);
    #pragma unroll
    for (int p = 0; p < PP; p++) acc[p] += __shfl_xor(acc[p], off, 64);
  }
  if (lane == 0) {
    float inv = 1.0f / fmaxf(sqrtf(ss), 1e-12f);
    size_t base = ((size_t)b * PP) * LL + l;
    #pragma unroll
    for (int p = 0; p < PP; p++) cs[base + (size_t)p * LL] = acc[p] * inv;
  }
}

// ---------------- kernel 2: MDN per 2 rows: h, pi/mu/sigma, top-5, NLL, mask, denom
__global__ __launch_bounds__(256) void k2_mdn(
    const float* __restrict__ cs_g, const float* __restrict__ W1, const float* __restrict__ b1,
    const float* __restrict__ Wpi, const float* __restrict__ bpi,
    const float* __restrict__ Wmu, const float* __restrict__ bmu,
    const float* __restrict__ Wsig, const float* __restrict__ bsig,
    float* __restrict__ mask_g, float* __restrict__ denom_g, double* __restrict__ loss_sum)
{
  __shared__ float s_cs[2][LL];
  __shared__ float s_h[2][LL];
  __shared__ float s_out[32];
  __shared__ float s_pi[2][KK], s_mu[2][KK], s_sig[2][KK];
  __shared__ float s_logpi[2][KK], s_logsig[2][KK], s_invsig[2][KK];
  __shared__ float s_dn[2][4];
  int tid = threadIdx.x, lane = tid & 63, wid = tid >> 6;
  int n0 = blockIdx.x * 2;
  for (int i = tid; i < 2 * LL; i += 256) s_cs[i >> 9][i & (LL - 1)] = cs_g[(size_t)n0 * LL + i];
  __syncthreads();
  // h = tanh(cs @ W1 + b1), each thread two columns via float2
  {
    int j0 = tid * 2;
    float a00 = 0, a01 = 0, a10 = 0, a11 = 0;
    for (int l = 0; l < LL; l++) {
      float2 w = *(const float2*)(W1 + (size_t)l * LL + j0);
      float c0 = s_cs[0][l], c1 = s_cs[1][l];
      a00 = fmaf(c0, w.x, a00); a01 = fmaf(c0, w.y, a01);
      a10 = fmaf(c1, w.x, a10); a11 = fmaf(c1, w.y, a11);
    }
    float bb0 = b1[j0], bb1 = b1[j0 + 1];
    s_h[0][j0] = tanhf(a00 + bb0); s_h[0][j0 + 1] = tanhf(a01 + bb1);
    s_h[1][j0] = tanhf(a10 + bb0); s_h[1][j0 + 1] = tanhf(a11 + bb1);
  }
  __syncthreads();
  // 30 projection dots (2 rows x {pi,mu,sig} x 5), double accum, one per wave round
  for (int o = wid; o < 30; o += 4) {
    int r = o / 15, rem = o % 15, pj = rem / 5, k = rem % 5;
    const float* W  = (pj == 0) ? Wpi : ((pj == 1) ? Wmu : Wsig);
    const float* bb = (pj == 0) ? bpi : ((pj == 1) ? bmu : bsig);
    double acc = 0;
    for (int l = lane; l < LL; l += 64) acc += (double)s_h[r][l] * (double)W[l * KK + k];
    #pragma unroll
    for (int off = 32; off; off >>= 1) acc += __shfl_xor(acc, off, 64);
    if (lane == 0) s_out[o] = (float)(acc + (double)bb[k]);
  }
  __syncthreads();
  if (tid < 2) {
    int r = tid;
    float x[KK], sh[KK], mx = -INFINITY;
    for (int k = 0; k < KK; k++) { x[k] = s_out[r * 15 + k]; mx = fmaxf(mx, x[k]); }
    float se = 0;
    for (int k = 0; k < KK; k++) { sh[k] = x[k] - mx; se += expf(sh[k]); }
    float lse = logf(se);
    for (int k = 0; k < KK; k++) {
      float lp = sh[k] - lse;
      s_logpi[r][k] = lp; s_pi[r][k] = expf(lp);
      float m = s_out[r * 15 + 5 + k];  s_mu[r][k] = m;
      float ls = s_out[r * 15 + 10 + k]; s_logsig[r][k] = ls;
      float sg = expf(ls); s_sig[r][k] = sg; s_invsig[r][k] = 1.0f / sg;
    }
  }
  __syncthreads();
  // top-5 argmax (JAX tie-break: larger value, else lower index) + NLL in double
  if (wid < 2) {
    int r = wid;
    float v[8];
    #pragma unroll
    for (int i = 0; i < 8; i++) v[i] = s_cs[r][lane + i * 64];
    float ys[KK];
    for (int it = 0; it < KK; ++it) {
      float bv = v[0]; int bi = lane;
      #pragma unroll
      for (int i = 1; i < 8; i++) { if (v[i] > bv) { bv = v[i]; bi = lane + i * 64; } }
      #pragma unroll
      for (int off = 32; off; off >>= 1) {
        float ov = __shfl_xor(bv, off, 64);
        int   oi = __shfl_xor(bi, off, 64);
        if (ov > bv || (ov == bv && oi < bi)) { bv = ov; bi = oi; }
      }
      ys[it] = (float)bi;
      if ((bi & 63) == lane) v[bi >> 6] = -INFINITY;
    }
    if (lane == 0) {
      double lsum = 0;
      for (int i = 0; i < KK; i++) {
        double y = (double)ys[i];
        double a[KK], m = -1e300;
        for (int j = 0; j < KK; j++) {
          double z = (y - (double)s_mu[r][j]) / (double)s_sig[r][j];
          a[j] = (double)s_logpi[r][j] - 0.5 * z * z - (double)s_logsig[r][j]
                 - 0.91893853320467274178;  // 0.5*log(2*pi)
          if (a[j] > m) m = a[j];
        }
        double se = 0;
        for (int j = 0; j < KK; j++) se += exp(a[j] - m);
        lsum += m + log(se);
      }
      atomicAdd(loss_sum, lsum);
    }
  }
  __syncthreads();
  // mask (mixture density over token positions) + row sums
  float part0 = 0, part1 = 0;
  for (int r = 0; r < 2; r++) {
    float p_local = 0;
    for (int l = tid; l < LL; l += 256) {
      float t = (float)l, d = 0;
      #pragma unroll
      for (int k = 0; k < KK; k++) {
        float zt = (t - s_mu[r][k]) * s_invsig[r][k];
        d += s_pi[r][k] * expf(-0.5f * zt * zt) * s_invsig[r][k];
      }
      d *= 0.39894228040143268f;   // 1/sqrt(2*pi)
      mask_g[(size_t)(n0 + r) * LL + l] = d;
      p_local += d;
    }
    if (r == 0) part0 = p_local; else part1 = p_local;
  }
  part0 = wredf(part0); part1 = wredf(part1);
  if (lane == 0) { s_dn[0][wid] = part0; s_dn[1][wid] = part1; }
  __syncthreads();
  if (tid < 2)
    denom_g[n0 + tid] = fmaxf(s_dn[tid][0] + s_dn[tid][1] + s_dn[tid][2] + s_dn[tid][3], 1e-9f);
}

// ---------------- kernel 3: Z[b,p,h] = sum_l hidden[b,l,h]*mask[b,p,l] /L /denom ----
__global__ __launch_bounds__(512) void k3_pool(const float* __restrict__ hidden,
    const float* __restrict__ mask_g, const float* __restrict__ denom_g, float* __restrict__ Z)
{
  __shared__ float s_m[PP][LL];        // 10 KB
  __shared__ float s_acc[8][PP][128];  // 20 KB
  int b = blockIdx.x, hc = blockIdx.y;
  int tid = threadIdx.x, wid = tid >> 6, lane = tid & 63;
  for (int i = tid; i < PP * LL; i += 512) s_m[i >> 9][i & (LL - 1)] = mask_g[(size_t)b * PP * LL + i];
  __syncthreads();
  int h0 = hc * 128 + lane * 2;
  const float* hp = hidden + (size_t)b * LL * HH + h0;
  float a0[PP] = {0,0,0,0,0}, a1[PP] = {0,0,0,0,0};
  int lbase = wid * 64;
  #pragma unroll 4
  for (int i = 0; i < 64; i++) {
    int l = lbase + i;
    float2 hv = *(const float2*)(hp + (size_t)l * HH);
    #pragma unroll
    for (int p = 0; p < PP; p++) {
      float m = s_m[p][l];
      a0[p] = fmaf(hv.x, m, a0[p]); a1[p] = fmaf(hv.y, m, a1[p]);
    }
  }
  #pragma unroll
  for (int p = 0; p < PP; p++) { s_acc[wid][p][lane*2] = a0[p]; s_acc[wid][p][lane*2+1] = a1[p]; }
  __syncthreads();
  for (int o = tid; o < PP * 128; o += 512) {
    int p = o >> 7, hl = o & 127;
    float s = 0;
    #pragma unroll
    for (int w = 0; w < 8; w++) s += s_acc[w][p][hl];
    Z[((size_t)b * PP + p) * HH + hc * 128 + hl] = s * (1.0f / 512.0f) / denom_g[b * PP + p];
  }
}

// ---------------- kernel 4: cosine(Z[b,p], proto[p]) ----------------
__global__ __launch_bounds__(256) void k4_sim(const float* __restrict__ Zg,
    const float* __restrict__ proto, const float* __restrict__ pnorm, float* __restrict__ sim)
{
  int tid = threadIdx.x, lane = tid & 63, wid = tid >> 6;
  int g = blockIdx.x * 4 + wid;   // 0..159
  int p = g % PP;
  const float* z = Zg + (size_t)g * HH;
  const float* pr = proto + p * HH;
  float num = 0, zz = 0;
  for (int i = lane; i < HH; i += 64) { float zv = z[i]; num = fmaf(zv, pr[i], num); zz = fmaf(zv, zv, zz); }
  num = wredf(num); zz = wredf(zz);
  if (lane == 0) sim[g] = num / fmaxf(sqrtf(zz) * pnorm[p], 1e-6f);
}

// ---------------- kernel 5: logits + loss write ----------------
__global__ void k5_head(const float* __restrict__ sim, const float* __restrict__ fcW,
    const float* __restrict__ fcb, const double* __restrict__ loss_sum, float* __restrict__ out)
{
  int tid = threadIdx.x;
  if (tid < BB * CC) {
    int b = tid >> 2, c = tid & 3;
    float s = fcb[c];
    #pragma unroll
    for (int p = 0; p < PP; p++) s = fmaf(sim[b * PP + p], fcW[p * CC + c], s);
    out[tid] = s;
  }
  if (tid == 0) out[128] = (float)(-loss_sum[0] / 800.0);
}

extern "C" void kernel_launch(void* const* d_in, const int* in_sizes, int n_in,
                              void* d_out, int out_size, void* d_ws, size_t ws_size,
                              hipStream_t stream)
{
  const float* emb   = (const float*)d_in[0];
  const float* hid   = (const float*)d_in[1];
  const float* proto = (const float*)d_in[2];
  const float* W1    = (const float*)d_in[3];
  const float* b1    = (const float*)d_in[4];
  const float* Wpi   = (const float*)d_in[5];
  const float* bpi   = (const float*)d_in[6];
  const float* Wmu   = (const float*)d_in[7];
  const float* bmu   = (const float*)d_in[8];
  const float* Wsig  = (const float*)d_in[9];
  const float* bsig  = (const float*)d_in[10];
  const float* fcW   = (const float*)d_in[11];
  const float* fcb   = (const float*)d_in[12];
  float* out = (float*)d_out;

  double* loss = (double*)d_ws;         // 8B at offset 0
  float* wsf   = (float*)d_ws;
  float* pnorm = wsf + 4;               // 5
  float* p_n   = wsf + 12;              // 3840 (16B aligned: byte 48)
  float* cs    = p_n + PP * HH;         // 160*512
  float* maskb = cs + (size_t)NN * LL;  // 160*512
  float* denom = maskb + (size_t)NN * LL; // 160
  float* Zb    = denom + NN;            // 160*768
  float* simb  = Zb + (size_t)NN * HH;  // 160

  k0_init<<<1, 256, 0, stream>>>(proto, p_n, pnorm, loss, out);
  k1_cs<<<4096, 256, 0, stream>>>(emb, p_n, cs);
  k2_mdn<<<NN / 2, 256, 0, stream>>>(cs, W1, b1, Wpi, bpi, Wmu, bmu, Wsig, bsig, maskb, denom, loss);
  k3_pool<<<dim3(BB, 6), 512, 0, stream>>>(hid, maskb, denom, Zb);
  k4_sim<<<NN / 4, 256, 0, stream>>>(Zb, proto, pnorm, simb);
  k5_head<<<1, 128, 0, stream>>>(simb, fcW, fcb, loss, out);
}

// Round 3
// 193.830 us; speedup vs baseline: 1.1741x; 1.1741x over previous
//
#include <hip/hip_runtime.h>
#include <math.h>

#define BB 32
#define LL 512
#define HH 768
#define PP 5
#define KK 5
#define CC 4
#define NN (BB*PP)   // 160

__device__ __forceinline__ float wredf(float v) {
  #pragma unroll
  for (int off = 32; off; off >>= 1) v += __shfl_xor(v, off, 64);
  return v;
}
__device__ __forceinline__ double wredd(double v) {
  #pragma unroll
  for (int off = 32; off; off >>= 1) v += __shfl_xor(v, off, 64);
  return v;
}

// ---- kernel 0: 15 blocks. bid<5: pnorm[p] + p_n[p]. bid>=5: diversity pair partial.
__global__ __launch_bounds__(256) void k0_init(const float* __restrict__ proto,
    float* __restrict__ p_n, float* __restrict__ pnorm, float* __restrict__ div_parts)
{
  __shared__ float s_red[4];
  int tid = threadIdx.x, lane = tid & 63, wid = tid >> 6;
  int bid = blockIdx.x;
  if (bid < PP) {
    int p = bid;
    float ss = 0;
    for (int i = tid; i < HH; i += 256) { float v = proto[p*HH + i]; ss = fmaf(v, v, ss); }
    ss = wredf(ss);
    if (lane == 0) s_red[wid] = ss;
    __syncthreads();
    float nrm = sqrtf(s_red[0] + s_red[1] + s_red[2] + s_red[3]);
    if (tid == 0) pnorm[p] = nrm;
    float inv = 1.0f / fmaxf(nrm, 1e-12f);
    for (int i = tid; i < HH; i += 256) p_n[p*HH + i] = proto[p*HH + i] * inv;
  } else {
    const int pi_[10] = {0,0,0,0,1,1,1,2,2,3};
    const int pj_[10] = {1,2,3,4,2,3,4,3,4,4};
    int q = bid - PP, i = pi_[q], j = pj_[q];
    float ss = 0;
    for (int t = tid; t < HH; t += 256) {
      float d = proto[i*HH + t] - proto[j*HH + t];
      ss = fmaf(d, d, ss);
    }
    ss = wredf(ss);
    if (lane == 0) s_red[wid] = ss;
    __syncthreads();
    if (tid == 0) {
      float D = sqrtf(fmaxf(s_red[0] + s_red[1] + s_red[2] + s_red[3], 1e-12f));
      div_parts[q] = fmaxf(0.5f - D, 0.0f);
    }
  }
}

// ---- kernel 1: wave per (b,l). p_n is 15 KB -> L1-resident, no LDS staging.
__global__ __launch_bounds__(256) void k1_cs(const float* __restrict__ emb,
    const float* __restrict__ p_n, float* __restrict__ cs)
{
  int tid = threadIdx.x, lane = tid & 63, wid = tid >> 6;
  int gw = blockIdx.x * 4 + wid;        // 0..16383
  int b = gw >> 9, l = gw & 511;
  const float4* e4  = (const float4*)(emb + ((size_t)b * LL + l) * HH);
  const float4* pn4 = (const float4*)p_n;
  float ss = 0, acc[PP] = {0, 0, 0, 0, 0};
  #pragma unroll
  for (int i = 0; i < 3; i++) {
    int idx = lane + i * 64;
    float4 x = e4[idx];
    ss = fmaf(x.x, x.x, fmaf(x.y, x.y, fmaf(x.z, x.z, fmaf(x.w, x.w, ss))));
    #pragma unroll
    for (int p = 0; p < PP; p++) {
      float4 w = pn4[p * (HH/4) + idx];
      acc[p] = fmaf(x.x, w.x, fmaf(x.y, w.y, fmaf(x.z, w.z, fmaf(x.w, w.w, acc[p]))));
    }
  }
  #pragma unroll
  for (int off = 32; off; off >>= 1) {
    ss += __shfl_xor(ss, off, 64);
    #pragma unroll
    for (int p = 0; p < PP; p++) acc[p] += __shfl_xor(acc[p], off, 64);
  }
  if (lane == 0) {
    float inv = 1.0f / fmaxf(sqrtf(ss), 1e-12f);
    size_t base = ((size_t)b * PP) * LL + l;
    #pragma unroll
    for (int p = 0; p < PP; p++) cs[base + (size_t)p * LL] = acc[p] * inv;
  }
}

// ---- kernel 2a: h[n][j] = tanh(cs[n] . W1[:,j] + b1[j]). 160 blocks x 512 thr.
__global__ __launch_bounds__(512) void k2a_gemm(const float* __restrict__ cs_g,
    const float* __restrict__ W1, const float* __restrict__ b1, float* __restrict__ h_g)
{
  __shared__ float s_cs[LL];
  int tid = threadIdx.x, n = blockIdx.x;
  s_cs[tid] = cs_g[(size_t)n * LL + tid];
  __syncthreads();
  int j = tid;
  float a0 = 0, a1 = 0, a2 = 0, a3 = 0;
  #pragma unroll 4
  for (int l = 0; l < LL; l += 4) {
    a0 = fmaf(s_cs[l+0], W1[(size_t)(l+0) * LL + j], a0);
    a1 = fmaf(s_cs[l+1], W1[(size_t)(l+1) * LL + j], a1);
    a2 = fmaf(s_cs[l+2], W1[(size_t)(l+2) * LL + j], a2);
    a3 = fmaf(s_cs[l+3], W1[(size_t)(l+3) * LL + j], a3);
  }
  h_g[(size_t)n * LL + j] = tanhf((a0 + a1) + (a2 + a3) + b1[j]);
}

// ---- kernel 2b: per-row MDN: projections, softmax, top-5, NLL, mask, denom.
__global__ __launch_bounds__(256) void k2b_mdn(
    const float* __restrict__ cs_g, const float* __restrict__ h_g,
    const float* __restrict__ Wpi, const float* __restrict__ bpi,
    const float* __restrict__ Wmu, const float* __restrict__ bmu,
    const float* __restrict__ Wsig, const float* __restrict__ bsig,
    float* __restrict__ mask_g, float* __restrict__ denom_g, double* __restrict__ loss_rows)
{
  __shared__ float s_cs[LL], s_h[LL];
  __shared__ float s_out[16];
  __shared__ float s_pi[KK], s_mu[KK], s_sig[KK], s_logpi[KK], s_logsig[KK], s_invsig[KK];
  __shared__ float s_dn[4];
  int tid = threadIdx.x, lane = tid & 63, wid = tid >> 6;
  int n = blockIdx.x;
  s_cs[tid]       = cs_g[(size_t)n * LL + tid];
  s_cs[tid + 256] = cs_g[(size_t)n * LL + tid + 256];
  s_h[tid]        = h_g[(size_t)n * LL + tid];
  s_h[tid + 256]  = h_g[(size_t)n * LL + tid + 256];
  __syncthreads();
  // 15 projection dots in double (4 waves, round-robin)
  for (int o = wid; o < 15; o += 4) {
    int pj = o / 5, k = o % 5;
    const float* W  = (pj == 0) ? Wpi : ((pj == 1) ? Wmu : Wsig);
    const float* bb = (pj == 0) ? bpi : ((pj == 1) ? bmu : bsig);
    double acc = 0;
    for (int l = lane; l < LL; l += 64) acc += (double)s_h[l] * (double)W[l * KK + k];
    acc = wredd(acc);
    if (lane == 0) s_out[o] = (float)(acc + (double)bb[k]);
  }
  __syncthreads();
  if (tid == 0) {
    float x[KK], sh[KK], mx = -INFINITY;
    for (int k = 0; k < KK; k++) { x[k] = s_out[k]; mx = fmaxf(mx, x[k]); }
    float se = 0;
    for (int k = 0; k < KK; k++) { sh[k] = x[k] - mx; se += expf(sh[k]); }
    float lse = logf(se);
    for (int k = 0; k < KK; k++) {
      float lp = sh[k] - lse;
      s_logpi[k] = lp; s_pi[k] = expf(lp);
      s_mu[k] = s_out[5 + k];
      float ls = s_out[10 + k]; s_logsig[k] = ls;
      float sg = expf(ls); s_sig[k] = sg; s_invsig[k] = 1.0f / sg;
    }
  }
  __syncthreads();
  // wave 0: top-5 (JAX tie-break: larger value, else lower index) + NLL (double)
  if (wid == 0) {
    float v[8];
    #pragma unroll
    for (int i = 0; i < 8; i++) v[i] = s_cs[lane + i * 64];
    float ys[KK];
    for (int it = 0; it < KK; ++it) {
      float bv = v[0]; int bi = lane;
      #pragma unroll
      for (int i = 1; i < 8; i++) { if (v[i] > bv) { bv = v[i]; bi = lane + i * 64; } }
      #pragma unroll
      for (int off = 32; off; off >>= 1) {
        float ov = __shfl_xor(bv, off, 64);
        int   oi = __shfl_xor(bi, off, 64);
        if (ov > bv || (ov == bv && oi < bi)) { bv = ov; bi = oi; }
      }
      ys[it] = (float)bi;
      if ((bi & 63) == lane) v[bi >> 6] = -INFINITY;
    }
    double ll = 0;
    if (lane < KK) {
      double y = (double)ys[lane];
      double a[KK], m = -1e300;
      for (int j = 0; j < KK; j++) {
        double z = (y - (double)s_mu[j]) / (double)s_sig[j];
        a[j] = (double)s_logpi[j] - 0.5 * z * z - (double)s_logsig[j]
               - 0.91893853320467274178;  // 0.5*log(2*pi)
        if (a[j] > m) m = a[j];
      }
      double se = 0;
      for (int j = 0; j < KK; j++) se += exp(a[j] - m);
      ll = m + log(se);
    }
    ll = wredd(ll);
    if (lane == 0) loss_rows[n] = ll;
  }
  __syncthreads();
  // mask + denom
  float p_local = 0;
  for (int l = tid; l < LL; l += 256) {
    float t = (float)l, d = 0;
    #pragma unroll
    for (int k = 0; k < KK; k++) {
      float zt = (t - s_mu[k]) * s_invsig[k];
      d += s_pi[k] * expf(-0.5f * zt * zt) * s_invsig[k];
    }
    d *= 0.39894228040143268f;   // 1/sqrt(2*pi)
    mask_g[(size_t)n * LL + l] = d;
    p_local += d;
  }
  p_local = wredf(p_local);
  if (lane == 0) s_dn[wid] = p_local;
  __syncthreads();
  if (tid == 0)
    denom_g[n] = fmaxf(s_dn[0] + s_dn[1] + s_dn[2] + s_dn[3], 1e-9f);
}

// ---- kernel 3: Z[b,p,h] = sum_l hidden[b,l,h]*mask[b,p,l] /L /denom ----
__global__ __launch_bounds__(512) void k3_pool(const float* __restrict__ hidden,
    const float* __restrict__ mask_g, const float* __restrict__ denom_g, float* __restrict__ Z)
{
  __shared__ float s_m[PP][LL];        // 10 KB
  __shared__ float s_acc[8][PP][128];  // 20 KB
  int b = blockIdx.x, hc = blockIdx.y;
  int tid = threadIdx.x, wid = tid >> 6, lane = tid & 63;
  for (int i = tid; i < PP * LL; i += 512) s_m[i >> 9][i & (LL - 1)] = mask_g[(size_t)b * PP * LL + i];
  __syncthreads();
  int h0 = hc * 128 + lane * 2;
  const float* hp = hidden + (size_t)b * LL * HH + h0;
  float a0[PP] = {0,0,0,0,0}, a1[PP] = {0,0,0,0,0};
  int lbase = wid * 64;
  #pragma unroll 8
  for (int i = 0; i < 64; i++) {
    int l = lbase + i;
    float2 hv = *(const float2*)(hp + (size_t)l * HH);
    #pragma unroll
    for (int p = 0; p < PP; p++) {
      float m = s_m[p][l];
      a0[p] = fmaf(hv.x, m, a0[p]); a1[p] = fmaf(hv.y, m, a1[p]);
    }
  }
  #pragma unroll
  for (int p = 0; p < PP; p++) { s_acc[wid][p][lane*2] = a0[p]; s_acc[wid][p][lane*2+1] = a1[p]; }
  __syncthreads();
  for (int o = tid; o < PP * 128; o += 512) {
    int p = o >> 7, hl = o & 127;
    float s = 0;
    #pragma unroll
    for (int w = 0; w < 8; w++) s += s_acc[w][p][hl];
    Z[((size_t)b * PP + p) * HH + hc * 128 + hl] = s * (1.0f / 512.0f) / denom_g[b * PP + p];
  }
}

// ---- kernel 4: cosine(Z[b,p], proto[p]) ----
__global__ __launch_bounds__(256) void k4_sim(const float* __restrict__ Zg,
    const float* __restrict__ proto, const float* __restrict__ pnorm, float* __restrict__ sim)
{
  int tid = threadIdx.x, lane = tid & 63, wid = tid >> 6;
  int g = blockIdx.x * 4 + wid;   // 0..159
  int p = g % PP;
  const float* z = Zg + (size_t)g * HH;
  const float* pr = proto + p * HH;
  float num = 0, zz = 0;
  for (int i = lane; i < HH; i += 64) { float zv = z[i]; num = fmaf(zv, pr[i], num); zz = fmaf(zv, zv, zz); }
  num = wredf(num); zz = wredf(zz);
  if (lane == 0) sim[g] = num / fmaxf(sqrtf(zz) * pnorm[p], 1e-6f);
}

// ---- kernel 5: logits + loss/diversity reduction ----
__global__ __launch_bounds__(256) void k5_head(const float* __restrict__ sim,
    const float* __restrict__ fcW, const float* __restrict__ fcb,
    const double* __restrict__ loss_rows, const float* __restrict__ div_parts,
    float* __restrict__ out)
{
  int tid = threadIdx.x, lane = tid & 63, wid = tid >> 6;
  if (tid < BB * CC) {
    int b = tid >> 2, c = tid & 3;
    float s = fcb[c];
    #pragma unroll
    for (int p = 0; p < PP; p++) s = fmaf(sim[b * PP + p], fcW[p * CC + c], s);
    out[tid] = s;
  }
  if (wid == 2) {
    double s = 0;
    for (int i = lane; i < NN; i += 64) s += loss_rows[i];
    s = wredd(s);
    if (lane == 0) out[128] = (float)(-s / 800.0);
  }
  if (wid == 3) {
    float s = (lane < 10) ? div_parts[lane] : 0.0f;
    s = wredf(s);
    if (lane == 0) out[129] = s;
  }
}

extern "C" void kernel_launch(void* const* d_in, const int* in_sizes, int n_in,
                              void* d_out, int out_size, void* d_ws, size_t ws_size,
                              hipStream_t stream)
{
  const float* emb   = (const float*)d_in[0];
  const float* hid   = (const float*)d_in[1];
  const float* proto = (const float*)d_in[2];
  const float* W1    = (const float*)d_in[3];
  const float* b1    = (const float*)d_in[4];
  const float* Wpi   = (const float*)d_in[5];
  const float* bpi   = (const float*)d_in[6];
  const float* Wmu   = (const float*)d_in[7];
  const float* bmu   = (const float*)d_in[8];
  const float* Wsig  = (const float*)d_in[9];
  const float* bsig  = (const float*)d_in[10];
  const float* fcW   = (const float*)d_in[11];
  const float* fcb   = (const float*)d_in[12];
  float* out = (float*)d_out;

  // ws layout (floats); loss_rows is double[160] at offset 0.
  double* loss_rows = (double*)d_ws;                 // 160 doubles = 320 floats
  float* wsf   = (float*)d_ws;
  float* divp  = wsf + 320;                          // 10
  float* pnorm = wsf + 330;                          // 5
  float* p_n   = wsf + 336;                          // 3840 (byte 1344, 16B aligned)
  float* cs    = wsf + 4176;                         // 81920
  float* h_ws  = cs + (size_t)NN * LL;               // 81920
  float* maskb = h_ws + (size_t)NN * LL;             // 81920
  float* denom = maskb + (size_t)NN * LL;            // 160
  float* simb  = denom + NN;                         // 160
  float* Zb    = cs;                                 // alias: cs+h dead before k3 writes Z

  k0_init<<<15, 256, 0, stream>>>(proto, p_n, pnorm, divp);
  k1_cs<<<4096, 256, 0, stream>>>(emb, p_n, cs);
  k2a_gemm<<<NN, 512, 0, stream>>>(cs, W1, b1, h_ws);
  k2b_mdn<<<NN, 256, 0, stream>>>(cs, h_ws, Wpi, bpi, Wmu, bmu, Wsig, bsig, maskb, denom, loss_rows);
  k3_pool<<<dim3(BB, 6), 512, 0, stream>>>(hid, maskb, denom, Zb);
  k4_sim<<<NN / 4, 256, 0, stream>>>(Zb, proto, pnorm, simb);
  k5_head<<<1, 256, 0, stream>>>(simb, fcW, fcb, loss_rows, divp, out);
}